// Round 1
// baseline (3809.723 us; speedup 1.0000x reference)
//
#include <hip/hip_runtime.h>
#include <math.h>

// Problem constants
#define BDIM 4096
#define NEXP 8
#define HDIM 1024
#define XDIM 800
#define ZDIM 64
#define ODIM 768
#define GH   128

// Tile config
#define BM 64
#define BN 64
#define BK 32
#define PAD 68   // LDS row stride (floats): BM + 4; keeps float4 alignment (68%4==0)

__device__ __forceinline__ float elu_act(float x) {
    return x > 0.0f ? x : expm1f(x);
}

// ---------------------------------------------------------------------------
// Generic tiled GEMM with implicit concat input: C = act(cat(A,Z) @ W^T + bias)
//   A: [M, KH] row-major, Z: [M, KZ] row-major (may be null if KZ==0)
//   W: [N, K] row-major (K = KH + KZ), bias: [N]
// BK=32 chunks never straddle the KH boundary (KH % 32 == 0 for all uses).
// ---------------------------------------------------------------------------
template<int ACT>
__global__ __launch_bounds__(256)
void gemm_cat(const float* __restrict__ srcA, int KH,
              const float* __restrict__ srcZ, int KZ,
              const float* __restrict__ W, const float* __restrict__ bias,
              float* __restrict__ dst, int N)
{
    __shared__ float lds_a[BK][PAD];
    __shared__ float lds_b[BK][PAD];
    const int K = KH + KZ;
    const int row0 = blockIdx.x * BM;
    const int col0 = blockIdx.y * BN;
    const int tid = threadIdx.x;
    const int tx = tid & 15, ty = tid >> 4;

    float acc[4][4] = {};

    for (int k0 = 0; k0 < K; k0 += BK) {
        // stage A tile, transposed to lds_a[k][m]
        #pragma unroll
        for (int it = 0; it < 2; ++it) {
            int idx = tid + it * 256;          // 0..511
            int r = idx >> 3;                  // 0..63
            int f = idx & 7;                   // 0..7
            int k = k0 + f * 4;
            const float* src; int col;
            if (k < KH) { src = srcA + (size_t)(row0 + r) * KH; col = k; }
            else        { src = srcZ + (size_t)(row0 + r) * KZ; col = k - KH; }
            float4 v = *(const float4*)(src + col);
            lds_a[f*4+0][r] = v.x;
            lds_a[f*4+1][r] = v.y;
            lds_a[f*4+2][r] = v.z;
            lds_a[f*4+3][r] = v.w;
        }
        // stage W tile, transposed to lds_b[k][n]
        #pragma unroll
        for (int it = 0; it < 2; ++it) {
            int idx = tid + it * 256;
            int c = idx >> 3;
            int f = idx & 7;
            int k = k0 + f * 4;
            float4 v = *(const float4*)(W + (size_t)(col0 + c) * K + k);
            lds_b[f*4+0][c] = v.x;
            lds_b[f*4+1][c] = v.y;
            lds_b[f*4+2][c] = v.z;
            lds_b[f*4+3][c] = v.w;
        }
        __syncthreads();
        #pragma unroll
        for (int j = 0; j < BK; ++j) {
            float4 a4 = *(const float4*)&lds_a[j][ty*4];
            float4 b4 = *(const float4*)&lds_b[j][tx*4];
            float a[4] = {a4.x, a4.y, a4.z, a4.w};
            float b[4] = {b4.x, b4.y, b4.z, b4.w};
            #pragma unroll
            for (int i = 0; i < 4; ++i)
                #pragma unroll
                for (int jj = 0; jj < 4; ++jj)
                    acc[i][jj] += a[i] * b[jj];
        }
        __syncthreads();
    }

    #pragma unroll
    for (int i = 0; i < 4; ++i) {
        int r = row0 + ty*4 + i;
        float vals[4];
        #pragma unroll
        for (int j = 0; j < 4; ++j) {
            float v = acc[i][j] + bias[col0 + tx*4 + j];
            vals[j] = (ACT == 1) ? elu_act(v) : v;
        }
        *(float4*)(dst + (size_t)r * N + col0 + tx*4) =
            make_float4(vals[0], vals[1], vals[2], vals[3]);
    }
}

// ---------------------------------------------------------------------------
// Gating layer 3 + softmax: bc[b,:] = softmax(g2[b,:] @ Wg3^T + bg3)
// One block = 32 rows; thread (rowl, o) computes one logit; softmax via shfl.
// ---------------------------------------------------------------------------
__global__ __launch_bounds__(256)
void gating3_softmax(const float* __restrict__ g2, const float* __restrict__ Wg3,
                     const float* __restrict__ bg3, float* __restrict__ bc)
{
    __shared__ float w[NEXP * GH];
    __shared__ float bsh[NEXP];
    const int tid = threadIdx.x;
    for (int i = tid; i < NEXP * GH; i += 256) w[i] = Wg3[i];
    if (tid < NEXP) bsh[tid] = bg3[tid];
    __syncthreads();

    const int rowl = tid >> 3;   // 0..31
    const int o    = tid & 7;    // 0..7
    const int row  = blockIdx.x * 32 + rowl;
    const float* g = g2 + (size_t)row * GH;

    float s = bsh[o];
    for (int k = 0; k < GH; ++k) s += g[k] * w[o * GH + k];

    // softmax across the 8 lanes sharing a row (lanes are contiguous in a wave)
    float m = s;
    #pragma unroll
    for (int d = 4; d >= 1; d >>= 1) m = fmaxf(m, __shfl_xor(m, d, 8));
    float e = expf(s - m);
    float sum = e;
    #pragma unroll
    for (int d = 4; d >= 1; d >>= 1) sum += __shfl_xor(sum, d, 8);

    bc[(size_t)blockIdx.x * 256 + tid] = e / sum;
}

// ---------------------------------------------------------------------------
// Blended expert layer:
//   out[b,o] = act( sum_e bc[b,e] * ( cat(A,Z)[b,:] . W[e,o,:] + bias[e,o] ) )
//   W: [E, N, K], bias: [E, N], bc: [M, E]
// Per-expert accumulator in registers, blended into the final acc per expert.
// ---------------------------------------------------------------------------
template<int ACT>
__global__ __launch_bounds__(256)
void blended_gemm(const float* __restrict__ srcA, int KH,
                  const float* __restrict__ srcZ, int KZ,
                  const float* __restrict__ W,
                  const float* __restrict__ bias,
                  const float* __restrict__ bc,
                  float* __restrict__ dst, int N)
{
    __shared__ float lds_a[BK][PAD];
    __shared__ float lds_b[BK][PAD];
    const int K = KH + KZ;
    const int row0 = blockIdx.x * BM;
    const int col0 = blockIdx.y * BN;
    const int tid = threadIdx.x;
    const int tx = tid & 15, ty = tid >> 4;

    float acc[4][4] = {};

    for (int e = 0; e < NEXP; ++e) {
        const float* We = W + (size_t)e * N * K;
        float acce[4][4] = {};

        for (int k0 = 0; k0 < K; k0 += BK) {
            #pragma unroll
            for (int it = 0; it < 2; ++it) {
                int idx = tid + it * 256;
                int r = idx >> 3;
                int f = idx & 7;
                int k = k0 + f * 4;
                const float* src; int col;
                if (k < KH) { src = srcA + (size_t)(row0 + r) * KH; col = k; }
                else        { src = srcZ + (size_t)(row0 + r) * KZ; col = k - KH; }
                float4 v = *(const float4*)(src + col);
                lds_a[f*4+0][r] = v.x;
                lds_a[f*4+1][r] = v.y;
                lds_a[f*4+2][r] = v.z;
                lds_a[f*4+3][r] = v.w;
            }
            #pragma unroll
            for (int it = 0; it < 2; ++it) {
                int idx = tid + it * 256;
                int c = idx >> 3;
                int f = idx & 7;
                int k = k0 + f * 4;
                float4 v = *(const float4*)(We + (size_t)(col0 + c) * K + k);
                lds_b[f*4+0][c] = v.x;
                lds_b[f*4+1][c] = v.y;
                lds_b[f*4+2][c] = v.z;
                lds_b[f*4+3][c] = v.w;
            }
            __syncthreads();
            #pragma unroll
            for (int j = 0; j < BK; ++j) {
                float4 a4 = *(const float4*)&lds_a[j][ty*4];
                float4 b4 = *(const float4*)&lds_b[j][tx*4];
                float a[4] = {a4.x, a4.y, a4.z, a4.w};
                float b[4] = {b4.x, b4.y, b4.z, b4.w};
                #pragma unroll
                for (int i = 0; i < 4; ++i)
                    #pragma unroll
                    for (int jj = 0; jj < 4; ++jj)
                        acce[i][jj] += a[i] * b[jj];
            }
            __syncthreads();
        }

        // blend: acc += bc[b,e] * (acce + bias_e)
        float bcv[4];
        #pragma unroll
        for (int i = 0; i < 4; ++i)
            bcv[i] = bc[(size_t)(row0 + ty*4 + i) * NEXP + e];
        const float* be = bias + (size_t)e * N;
        #pragma unroll
        for (int i = 0; i < 4; ++i)
            #pragma unroll
            for (int j = 0; j < 4; ++j)
                acc[i][j] += bcv[i] * (acce[i][j] + be[col0 + tx*4 + j]);
    }

    #pragma unroll
    for (int i = 0; i < 4; ++i) {
        int r = row0 + ty*4 + i;
        float vals[4];
        #pragma unroll
        for (int j = 0; j < 4; ++j) {
            float v = acc[i][j];
            vals[j] = (ACT == 1) ? elu_act(v) : v;
        }
        *(float4*)(dst + (size_t)r * N + col0 + tx*4) =
            make_float4(vals[0], vals[1], vals[2], vals[3]);
    }
}

// ---------------------------------------------------------------------------
extern "C" void kernel_launch(void* const* d_in, const int* in_sizes, int n_in,
                              void* d_out, int out_size, void* d_ws, size_t ws_size,
                              hipStream_t stream)
{
    const float* x   = (const float*)d_in[0];
    const float* z   = (const float*)d_in[1];
    const float* Wg1 = (const float*)d_in[2];
    const float* bg1 = (const float*)d_in[3];
    const float* Wg2 = (const float*)d_in[4];
    const float* bg2 = (const float*)d_in[5];
    const float* Wg3 = (const float*)d_in[6];
    const float* bg3 = (const float*)d_in[7];
    const float* W0  = (const float*)d_in[8];
    const float* b0  = (const float*)d_in[9];
    const float* W1  = (const float*)d_in[10];
    const float* b1  = (const float*)d_in[11];
    const float* W2  = (const float*)d_in[12];
    const float* b2  = (const float*)d_in[13];
    const float* W3  = (const float*)d_in[14];
    const float* b3  = (const float*)d_in[15];
    float* out = (float*)d_out;

    // workspace layout (floats): h_a[4096*1024] h_b[4096*1024] g1[4096*128]
    //                            g2[4096*128] bc[4096*8]   -> ~37.9 MB total
    float* ws  = (float*)d_ws;
    float* h_a = ws;
    float* h_b = h_a + (size_t)BDIM * HDIM;
    float* g1  = h_b + (size_t)BDIM * HDIM;
    float* g2  = g1  + (size_t)BDIM * GH;
    float* bcw = g2  + (size_t)BDIM * GH;

    dim3 blk(256);

    // gating MLP
    gemm_cat<1><<<dim3(BDIM/BM, GH/BN), blk, 0, stream>>>(x, XDIM, z, ZDIM, Wg1, bg1, g1, GH);
    gemm_cat<1><<<dim3(BDIM/BM, GH/BN), blk, 0, stream>>>(g1, GH, nullptr, 0, Wg2, bg2, g2, GH);
    gating3_softmax<<<dim3(BDIM/32), blk, 0, stream>>>(g2, Wg3, bg3, bcw);

    // blended expert layers
    blended_gemm<1><<<dim3(BDIM/BM, HDIM/BN), blk, 0, stream>>>(x,   XDIM, z, ZDIM, W0, b0, bcw, h_a, HDIM);
    blended_gemm<1><<<dim3(BDIM/BM, HDIM/BN), blk, 0, stream>>>(h_a, HDIM, z, ZDIM, W1, b1, bcw, h_b, HDIM);
    blended_gemm<1><<<dim3(BDIM/BM, HDIM/BN), blk, 0, stream>>>(h_b, HDIM, z, ZDIM, W2, b2, bcw, h_a, HDIM);
    blended_gemm<0><<<dim3(BDIM/BM, ODIM/BN), blk, 0, stream>>>(h_a, HDIM, nullptr, 0, W3, b3, bcw, out, ODIM);
}

// Round 2
// 2179.393 us; speedup vs baseline: 1.7481x; 1.7481x over previous
//
#include <hip/hip_runtime.h>
#include <math.h>

// Problem constants
#define BDIM 4096
#define NEXP 8
#define HDIM 1024
#define XDIM 800
#define ZDIM 64
#define ODIM 768
#define GH   128

typedef _Float16 f16;
typedef f16   f16x8 __attribute__((ext_vector_type(8)));
typedef f16   f16x4 __attribute__((ext_vector_type(4)));
typedef float f32x4 __attribute__((ext_vector_type(4)));

__device__ __forceinline__ float elu_act(float x) {
    return x > 0.0f ? x : expm1f(x);
}

// ===========================================================================
// fp32 tiled GEMM with implicit concat input (gating MLP only — small)
// C = act(cat(A,Z) @ W^T + bias);  BK chunks never straddle KH (KH%32==0)
// ===========================================================================
#define BMg 64
#define BNg 64
#define BKg 32
#define PADg 68

template<int ACT>
__global__ __launch_bounds__(256)
void gemm_cat(const float* __restrict__ srcA, int KH,
              const float* __restrict__ srcZ, int KZ,
              const float* __restrict__ W, const float* __restrict__ bias,
              float* __restrict__ dst, int N)
{
    __shared__ float lds_a[BKg][PADg];
    __shared__ float lds_b[BKg][PADg];
    const int K = KH + KZ;
    const int row0 = blockIdx.x * BMg;
    const int col0 = blockIdx.y * BNg;
    const int tid = threadIdx.x;
    const int tx = tid & 15, ty = tid >> 4;

    float acc[4][4] = {};

    for (int k0 = 0; k0 < K; k0 += BKg) {
        #pragma unroll
        for (int it = 0; it < 2; ++it) {
            int idx = tid + it * 256;
            int r = idx >> 3;
            int f = idx & 7;
            int k = k0 + f * 4;
            const float* src; int col;
            if (k < KH) { src = srcA + (size_t)(row0 + r) * KH; col = k; }
            else        { src = srcZ + (size_t)(row0 + r) * KZ; col = k - KH; }
            float4 v = *(const float4*)(src + col);
            lds_a[f*4+0][r] = v.x; lds_a[f*4+1][r] = v.y;
            lds_a[f*4+2][r] = v.z; lds_a[f*4+3][r] = v.w;
        }
        #pragma unroll
        for (int it = 0; it < 2; ++it) {
            int idx = tid + it * 256;
            int c = idx >> 3;
            int f = idx & 7;
            int k = k0 + f * 4;
            float4 v = *(const float4*)(W + (size_t)(col0 + c) * K + k);
            lds_b[f*4+0][c] = v.x; lds_b[f*4+1][c] = v.y;
            lds_b[f*4+2][c] = v.z; lds_b[f*4+3][c] = v.w;
        }
        __syncthreads();
        #pragma unroll
        for (int j = 0; j < BKg; ++j) {
            float4 a4 = *(const float4*)&lds_a[j][ty*4];
            float4 b4 = *(const float4*)&lds_b[j][tx*4];
            float a[4] = {a4.x, a4.y, a4.z, a4.w};
            float b[4] = {b4.x, b4.y, b4.z, b4.w};
            #pragma unroll
            for (int i = 0; i < 4; ++i)
                #pragma unroll
                for (int jj = 0; jj < 4; ++jj)
                    acc[i][jj] += a[i] * b[jj];
        }
        __syncthreads();
    }

    #pragma unroll
    for (int i = 0; i < 4; ++i) {
        int r = row0 + ty*4 + i;
        float vals[4];
        #pragma unroll
        for (int j = 0; j < 4; ++j) {
            float v = acc[i][j] + bias[col0 + tx*4 + j];
            vals[j] = (ACT == 1) ? elu_act(v) : v;
        }
        *(float4*)(dst + (size_t)r * N + col0 + tx*4) =
            make_float4(vals[0], vals[1], vals[2], vals[3]);
    }
}

// ===========================================================================
// Gating layer 3 + softmax (fp32): bc = softmax(g2 @ Wg3^T + bg3)
// ===========================================================================
__global__ __launch_bounds__(256)
void gating3_softmax(const float* __restrict__ g2, const float* __restrict__ Wg3,
                     const float* __restrict__ bg3, float* __restrict__ bc)
{
    __shared__ float w[NEXP * GH];
    __shared__ float bsh[NEXP];
    const int tid = threadIdx.x;
    for (int i = tid; i < NEXP * GH; i += 256) w[i] = Wg3[i];
    if (tid < NEXP) bsh[tid] = bg3[tid];
    __syncthreads();

    const int rowl = tid >> 3;
    const int o    = tid & 7;
    const int row  = blockIdx.x * 32 + rowl;
    const float* g = g2 + (size_t)row * GH;

    float s = bsh[o];
    for (int k = 0; k < GH; ++k) s += g[k] * w[o * GH + k];

    float m = s;
    #pragma unroll
    for (int d = 4; d >= 1; d >>= 1) m = fmaxf(m, __shfl_xor(m, d, 8));
    float e = expf(s - m);
    float sum = e;
    #pragma unroll
    for (int d = 4; d >= 1; d >>= 1) sum += __shfl_xor(sum, d, 8);

    bc[(size_t)blockIdx.x * 256 + tid] = e / sum;
}

// ===========================================================================
// Conversion kernels
// ===========================================================================
// xz16[row][0:800] = f16(x), xz16[row][800:864] = f16(z). 4 elems/thread.
__global__ __launch_bounds__(256)
void build_xz(const float* __restrict__ x, const float* __restrict__ z,
              f16* __restrict__ xz)
{
    int i = (blockIdx.x * 256 + threadIdx.x) * 4;      // over 4096*864
    int row = i / (XDIM + ZDIM);
    int col = i - row * (XDIM + ZDIM);
    float4 v;
    if (col < XDIM) v = *(const float4*)(x + (size_t)row * XDIM + col);
    else            v = *(const float4*)(z + (size_t)row * ZDIM + (col - XDIM));
    f16x4 o = { (f16)v.x, (f16)v.y, (f16)v.z, (f16)v.w };
    *(f16x4*)(xz + i) = o;
}

// Fill z-columns (1024..1087) of both hz buffers with f16(z).
__global__ __launch_bounds__(256)
void fill_z(const float* __restrict__ z, f16* __restrict__ hz_a,
            f16* __restrict__ hz_b)
{
    int i = (blockIdx.x * 256 + threadIdx.x) * 4;      // over 4096*64
    int row = i >> 6;
    int col = i & 63;
    float4 v = *(const float4*)(z + i);
    f16x4 o = { (f16)v.x, (f16)v.y, (f16)v.z, (f16)v.w };
    size_t off = (size_t)row * (HDIM + ZDIM) + HDIM + col;
    *(f16x4*)(hz_a + off) = o;
    *(f16x4*)(hz_b + off) = o;
}

// ===========================================================================
// Blended expert layer, fp16 MFMA:
//   out[b,o] = act( sum_e bc[b,e] * (A[b,:].W[e,o,:] + bias[e,o]) )
// A: fp16 [M][ldA] (K contiguous cols used), W: fp32 [E][N][K] (converted to
// f16 at LDS-staging time), bias fp32 [E][N], bc fp32 [M][8].
// Tile: 64(M) x 128(N) x 32(K); 4 waves 2x2; per-wave 32x64 via 2x4 MFMA tiles.
// ===========================================================================
template<int ACT, typename OT>
__global__ __launch_bounds__(256)
void blended_mfma(const f16* __restrict__ A, int ldA, int K,
                  const float* __restrict__ W,
                  const float* __restrict__ bias,
                  const float* __restrict__ bc,
                  OT* __restrict__ out, int N, int ldOut)
{
    // row stride 40 halves (80 B, 16B-aligned, 2-way bank alias max = free)
    __shared__ __align__(16) f16 a_lds[64][40];
    __shared__ __align__(16) f16 b_lds[128][40];
    __shared__ float bc_lds[64][8];
    __shared__ float bias_lds[8][128];

    const int tid  = threadIdx.x;
    const int row0 = blockIdx.x * 64;
    const int col0 = blockIdx.y * 128;
    const int wave = tid >> 6;
    const int lane = tid & 63;
    const int ln   = lane & 15;
    const int quad = lane >> 4;
    const int wy   = wave >> 1;        // m half (0..1)
    const int wx   = wave & 1;         // n half (0..1)

    // stage bc tile [64][8] and bias tile [8][128]
    for (int i = tid; i < 64 * 8; i += 256)
        bc_lds[i >> 3][i & 7] = bc[(size_t)(row0 + (i >> 3)) * NEXP + (i & 7)];
    for (int i = tid; i < 8 * 128; i += 256)
        bias_lds[i >> 7][i & 127] = bias[(size_t)(i >> 7) * N + col0 + (i & 127)];

    const int ar  = tid >> 2;          // 0..63
    const int akq = (tid & 3) * 8;     // 0,8,16,24

    f32x4 acc[2][4] = {};

    for (int e = 0; e < NEXP; ++e) {
        const float* We = W + (size_t)e * N * K;
        f32x4 acce[2][4] = {};

        for (int k0 = 0; k0 < K; k0 += 32) {
            __syncthreads();   // protect LDS from previous iteration's reads
            // A tile: 64 x 32 halves (global already fp16)
            *(f16x8*)&a_lds[ar][akq] =
                *(const f16x8*)(A + (size_t)(row0 + ar) * ldA + k0 + akq);
            // B tile: 128 x 32, fp32 global -> f16
            {
                const float* wr = We + (size_t)(col0 + ar) * K + k0 + akq;
                float4 w0 = *(const float4*)(wr);
                float4 w1 = *(const float4*)(wr + 4);
                f16x8 bv = { (f16)w0.x,(f16)w0.y,(f16)w0.z,(f16)w0.w,
                             (f16)w1.x,(f16)w1.y,(f16)w1.z,(f16)w1.w };
                *(f16x8*)&b_lds[ar][akq] = bv;
            }
            {
                const float* wr = We + (size_t)(col0 + 64 + ar) * K + k0 + akq;
                float4 w0 = *(const float4*)(wr);
                float4 w1 = *(const float4*)(wr + 4);
                f16x8 bv = { (f16)w0.x,(f16)w0.y,(f16)w0.z,(f16)w0.w,
                             (f16)w1.x,(f16)w1.y,(f16)w1.z,(f16)w1.w };
                *(f16x8*)&b_lds[64 + ar][akq] = bv;
            }
            __syncthreads();

            f16x8 af[2], bf[4];
            #pragma unroll
            for (int mi = 0; mi < 2; ++mi)
                af[mi] = *(const f16x8*)&a_lds[wy*32 + mi*16 + ln][quad*8];
            #pragma unroll
            for (int ni = 0; ni < 4; ++ni)
                bf[ni] = *(const f16x8*)&b_lds[wx*64 + ni*16 + ln][quad*8];
            #pragma unroll
            for (int mi = 0; mi < 2; ++mi)
                #pragma unroll
                for (int ni = 0; ni < 4; ++ni)
                    acce[mi][ni] = __builtin_amdgcn_mfma_f32_16x16x32_f16(
                        af[mi], bf[ni], acce[mi][ni], 0, 0, 0);
        }

        // blend: acc += bc[row,e] * acce   (fp32)
        #pragma unroll
        for (int mi = 0; mi < 2; ++mi) {
            float bv[4];
            #pragma unroll
            for (int r = 0; r < 4; ++r)
                bv[r] = bc_lds[wy*32 + mi*16 + quad*4 + r][e];
            #pragma unroll
            for (int ni = 0; ni < 4; ++ni)
                #pragma unroll
                for (int r = 0; r < 4; ++r)
                    acc[mi][ni][r] += bv[r] * acce[mi][ni][r];
        }
    }

    // epilogue: + sum_e bc*bias, activation, store
    #pragma unroll
    for (int mi = 0; mi < 2; ++mi)
        #pragma unroll
        for (int r = 0; r < 4; ++r) {
            int rl = wy*32 + mi*16 + quad*4 + r;
            size_t grow = (size_t)(row0 + rl) * ldOut;
            #pragma unroll
            for (int ni = 0; ni < 4; ++ni) {
                int cl = wx*64 + ni*16 + ln;
                float v = acc[mi][ni][r];
                #pragma unroll
                for (int e2 = 0; e2 < NEXP; ++e2)
                    v += bc_lds[rl][e2] * bias_lds[e2][cl];
                if (ACT) v = elu_act(v);
                out[grow + col0 + cl] = (OT)v;
            }
        }
}

// ===========================================================================
extern "C" void kernel_launch(void* const* d_in, const int* in_sizes, int n_in,
                              void* d_out, int out_size, void* d_ws, size_t ws_size,
                              hipStream_t stream)
{
    const float* x   = (const float*)d_in[0];
    const float* z   = (const float*)d_in[1];
    const float* Wg1 = (const float*)d_in[2];
    const float* bg1 = (const float*)d_in[3];
    const float* Wg2 = (const float*)d_in[4];
    const float* bg2 = (const float*)d_in[5];
    const float* Wg3 = (const float*)d_in[6];
    const float* bg3 = (const float*)d_in[7];
    const float* W0  = (const float*)d_in[8];
    const float* b0  = (const float*)d_in[9];
    const float* W1  = (const float*)d_in[10];
    const float* b1  = (const float*)d_in[11];
    const float* W2  = (const float*)d_in[12];
    const float* b2  = (const float*)d_in[13];
    const float* W3  = (const float*)d_in[14];
    const float* b3  = (const float*)d_in[15];
    float* out = (float*)d_out;

    // workspace layout (16B-aligned chunks), ~29.2 MB total:
    //   xz16 [4096][864] f16, hz_a [4096][1088] f16, hz_b [4096][1088] f16,
    //   g1 [4096][128] f32, g2 [4096][128] f32, bc [4096][8] f32
    char* ws = (char*)d_ws;
    f16*   xz16 = (f16*)ws;                 ws += (size_t)BDIM * (XDIM + ZDIM) * 2;
    f16*   hz_a = (f16*)ws;                 ws += (size_t)BDIM * (HDIM + ZDIM) * 2;
    f16*   hz_b = (f16*)ws;                 ws += (size_t)BDIM * (HDIM + ZDIM) * 2;
    float* g1   = (float*)ws;               ws += (size_t)BDIM * GH * 4;
    float* g2   = (float*)ws;               ws += (size_t)BDIM * GH * 4;
    float* bcw  = (float*)ws;

    dim3 blk(256);

    // input conversions
    build_xz<<<dim3(BDIM * (XDIM + ZDIM) / 4 / 256), blk, 0, stream>>>(x, z, xz16);
    fill_z<<<dim3(BDIM * ZDIM / 4 / 256), blk, 0, stream>>>(z, hz_a, hz_b);

    // gating MLP (fp32)
    gemm_cat<1><<<dim3(BDIM/BMg, GH/BNg), blk, 0, stream>>>(x, XDIM, z, ZDIM, Wg1, bg1, g1, GH);
    gemm_cat<1><<<dim3(BDIM/BMg, GH/BNg), blk, 0, stream>>>(g1, GH, nullptr, 0, Wg2, bg2, g2, GH);
    gating3_softmax<<<dim3(BDIM/32), blk, 0, stream>>>(g2, Wg3, bg3, bcw);

    // blended expert layers (fp16 MFMA)
    blended_mfma<1, f16><<<dim3(BDIM/64, HDIM/128), blk, 0, stream>>>(
        xz16, XDIM + ZDIM, XDIM + ZDIM, W0, b0, bcw, hz_a, HDIM, HDIM + ZDIM);
    blended_mfma<1, f16><<<dim3(BDIM/64, HDIM/128), blk, 0, stream>>>(
        hz_a, HDIM + ZDIM, HDIM + ZDIM, W1, b1, bcw, hz_b, HDIM, HDIM + ZDIM);
    blended_mfma<1, f16><<<dim3(BDIM/64, HDIM/128), blk, 0, stream>>>(
        hz_b, HDIM + ZDIM, HDIM + ZDIM, W2, b2, bcw, hz_a, HDIM, HDIM + ZDIM);
    blended_mfma<0, float><<<dim3(BDIM/64, ODIM/128), blk, 0, stream>>>(
        hz_a, HDIM + ZDIM, HDIM, W3, b3, bcw, out, ODIM, ODIM);
}

// Round 3
// 620.149 us; speedup vs baseline: 6.1432x; 3.5143x over previous
//
#include <hip/hip_runtime.h>
#include <math.h>

// Problem constants
#define BDIM 4096
#define NEXP 8
#define HDIM 1024
#define XDIM 800
#define ZDIM 64
#define ODIM 768
#define GH   128

typedef _Float16 f16;
typedef f16   f16x8 __attribute__((ext_vector_type(8)));
typedef f16   f16x4 __attribute__((ext_vector_type(4)));
typedef float f32x4 __attribute__((ext_vector_type(4)));

__device__ __forceinline__ float elu_act(float x) {
    return x > 0.0f ? x : expm1f(x);
}

// async global->LDS, 16B per lane; LDS dest is wave-uniform base + lane*16
__device__ __forceinline__ void glds16(const void* g, void* l) {
    __builtin_amdgcn_global_load_lds(
        (const __attribute__((address_space(1))) void*)g,
        (__attribute__((address_space(3))) void*)l, 16, 0, 0);
}

__device__ __forceinline__ f16x8 vscale(f16x8 v, f16 s) {
    f16x8 r;
    #pragma unroll
    for (int i = 0; i < 8; ++i) r[i] = v[i] * s;
    return r;
}

// ===========================================================================
// fp32 tiled GEMM with implicit concat input (gating MLP only — small)
// ===========================================================================
#define BMg 64
#define BNg 64
#define BKg 32
#define PADg 68

template<int ACT>
__global__ __launch_bounds__(256)
void gemm_cat(const float* __restrict__ srcA, int KH,
              const float* __restrict__ srcZ, int KZ,
              const float* __restrict__ W, const float* __restrict__ bias,
              float* __restrict__ dst, int N)
{
    __shared__ float lds_a[BKg][PADg];
    __shared__ float lds_b[BKg][PADg];
    const int K = KH + KZ;
    const int row0 = blockIdx.x * BMg;
    const int col0 = blockIdx.y * BNg;
    const int tid = threadIdx.x;
    const int tx = tid & 15, ty = tid >> 4;

    float acc[4][4] = {};

    for (int k0 = 0; k0 < K; k0 += BKg) {
        #pragma unroll
        for (int it = 0; it < 2; ++it) {
            int idx = tid + it * 256;
            int r = idx >> 3;
            int f = idx & 7;
            int k = k0 + f * 4;
            const float* src; int col;
            if (k < KH) { src = srcA + (size_t)(row0 + r) * KH; col = k; }
            else        { src = srcZ + (size_t)(row0 + r) * KZ; col = k - KH; }
            float4 v = *(const float4*)(src + col);
            lds_a[f*4+0][r] = v.x; lds_a[f*4+1][r] = v.y;
            lds_a[f*4+2][r] = v.z; lds_a[f*4+3][r] = v.w;
        }
        #pragma unroll
        for (int it = 0; it < 2; ++it) {
            int idx = tid + it * 256;
            int c = idx >> 3;
            int f = idx & 7;
            int k = k0 + f * 4;
            float4 v = *(const float4*)(W + (size_t)(col0 + c) * K + k);
            lds_b[f*4+0][c] = v.x; lds_b[f*4+1][c] = v.y;
            lds_b[f*4+2][c] = v.z; lds_b[f*4+3][c] = v.w;
        }
        __syncthreads();
        #pragma unroll
        for (int j = 0; j < BKg; ++j) {
            float4 a4 = *(const float4*)&lds_a[j][ty*4];
            float4 b4 = *(const float4*)&lds_b[j][tx*4];
            float a[4] = {a4.x, a4.y, a4.z, a4.w};
            float b[4] = {b4.x, b4.y, b4.z, b4.w};
            #pragma unroll
            for (int i = 0; i < 4; ++i)
                #pragma unroll
                for (int jj = 0; jj < 4; ++jj)
                    acc[i][jj] += a[i] * b[jj];
        }
        __syncthreads();
    }

    #pragma unroll
    for (int i = 0; i < 4; ++i) {
        int r = row0 + ty*4 + i;
        float vals[4];
        #pragma unroll
        for (int j = 0; j < 4; ++j) {
            float v = acc[i][j] + bias[col0 + tx*4 + j];
            vals[j] = (ACT == 1) ? elu_act(v) : v;
        }
        *(float4*)(dst + (size_t)r * N + col0 + tx*4) =
            make_float4(vals[0], vals[1], vals[2], vals[3]);
    }
}

// ===========================================================================
// Gating layer 3 + softmax (fp32)
// ===========================================================================
__global__ __launch_bounds__(256)
void gating3_softmax(const float* __restrict__ g2, const float* __restrict__ Wg3,
                     const float* __restrict__ bg3, float* __restrict__ bc)
{
    __shared__ float w[NEXP * GH];
    __shared__ float bsh[NEXP];
    const int tid = threadIdx.x;
    for (int i = tid; i < NEXP * GH; i += 256) w[i] = Wg3[i];
    if (tid < NEXP) bsh[tid] = bg3[tid];
    __syncthreads();

    const int rowl = tid >> 3;
    const int o    = tid & 7;
    const int row  = blockIdx.x * 32 + rowl;
    const float* g = g2 + (size_t)row * GH;

    float s = bsh[o];
    for (int k = 0; k < GH; ++k) s += g[k] * w[o * GH + k];

    float m = s;
    #pragma unroll
    for (int d = 4; d >= 1; d >>= 1) m = fmaxf(m, __shfl_xor(m, d, 8));
    float e = expf(s - m);
    float sum = e;
    #pragma unroll
    for (int d = 4; d >= 1; d >>= 1) sum += __shfl_xor(sum, d, 8);

    bc[(size_t)blockIdx.x * 256 + tid] = e / sum;
}

// ===========================================================================
// Helper kernels
// ===========================================================================
// Fill z-columns (1024..1087) of both hz buffers with f16(z) (unscaled).
__global__ __launch_bounds__(256)
void fill_z(const float* __restrict__ z, f16* __restrict__ hz_a,
            f16* __restrict__ hz_b)
{
    int i = (blockIdx.x * 256 + threadIdx.x) * 4;      // over 4096*64
    int row = i >> 6;
    int col = i & 63;
    float4 v = *(const float4*)(z + i);
    f16x4 o = { (f16)v.x, (f16)v.y, (f16)v.z, (f16)v.w };
    size_t off = (size_t)row * (HDIM + ZDIM) + HDIM + col;
    *(f16x4*)(hz_a + off) = o;
    *(f16x4*)(hz_b + off) = o;
}

// fp32 -> f16 weight conversion, 8 elements/thread
__global__ __launch_bounds__(256)
void w_to_f16(const float* __restrict__ src, f16* __restrict__ dst)
{
    size_t i = ((size_t)blockIdx.x * 256 + threadIdx.x) * 8;
    float4 v0 = *(const float4*)(src + i);
    float4 v1 = *(const float4*)(src + i + 4);
    f16x8 o = { (f16)v0.x,(f16)v0.y,(f16)v0.z,(f16)v0.w,
                (f16)v1.x,(f16)v1.y,(f16)v1.z,(f16)v1.w };
    *(f16x8*)(dst + i) = o;
}

// ===========================================================================
// Blended expert layer, "big-K" formulation:
//   out[b,o] = act( sum_e (bc[b,e]*A[b,:]) . Wf[e,o,:] + sum_e bc[b,e]*bias[e,o] )
// bc folded into the A *fragments* (per-lane scale) -> single accumulator set,
// A staged once per k-window, 64 MFMAs per barrier-pair.
// Tile: 64(M) x 128(N) x 32(K-window) x 8 experts resident in LDS.
// B via global_load_lds (f16 weights), XOR-swizzled k-chunks (conflict-free).
// ===========================================================================
template<int KE, int N, int ACT, int SRC, typename OT>
__global__ __launch_bounds__(256, 2)
void blended_big(const f16* __restrict__ A, int ldA,
                 const float* __restrict__ x, const float* __restrict__ z,
                 const f16* __restrict__ Wf, const float* __restrict__ bias,
                 const float* __restrict__ bc, OT* __restrict__ out, int ldOut)
{
    constexpr int NCT = N / 128;
    __shared__ __align__(16) f16 a_sh[64][40];            // pad 40: conflict-free
    __shared__ __align__(16) f16 b_sh[NEXP * 128 * 32];   // 64 KB, glds dest
    __shared__ float bc_sh[64][8];
    __shared__ float bias_sh[8][128];

    const int tid  = threadIdx.x;
    const int bid  = blockIdx.x;
    const int row0 = (bid / NCT) * 64;
    const int col0 = (bid % NCT) * 128;   // % 8 aligns col-slice with XCD L2
    const int wave = tid >> 6;
    const int lane = tid & 63;
    const int ln   = lane & 15;
    const int quad = lane >> 4;
    const int wy   = wave >> 1;           // m half
    const int wx   = wave & 1;            // n half

    // one-time staging of bc and bias tiles
    for (int i = tid; i < 64 * 8; i += 256)
        bc_sh[i >> 3][i & 7] = bc[(size_t)(row0 + (i >> 3)) * NEXP + (i & 7)];
    for (int i = tid; i < 8 * 128; i += 256)
        bias_sh[i >> 7][i & 127] = bias[(size_t)(i >> 7) * N + col0 + (i & 127)];

    // per-lane f16 bc scale factors for A-frag rows (m = wy*32 + mi*16 + ln)
    f16 bcf[2][8];
    #pragma unroll
    for (int mi = 0; mi < 2; ++mi) {
        const float* bp = bc + (size_t)(row0 + wy*32 + mi*16 + ln) * NEXP;
        #pragma unroll
        for (int e = 0; e < NEXP; ++e) bcf[mi][e] = (f16)bp[e];
    }

    // A staging coords: thread -> (row, k-chunk)
    const int ar = tid >> 2;              // 0..63
    const int ac = tid & 3;               // chunk of 8 halves
    // B staging lane constants: chunk i = j*64+lane -> p=j*16+(lane>>2), c=lane&3
    // stored k-chunk kc = c ^ ((p>>1)&3) = (lane&3) ^ ((lane>>3)&3)
    const int kcl  = (lane & 3) ^ ((lane >> 3) & 3);
    const int prow = lane >> 2;           // 0..15
    // per-wave: stage experts {2*wave, 2*wave+1}
    const f16* wb[2];
    #pragma unroll
    for (int ee = 0; ee < 2; ++ee)
        wb[ee] = Wf + ((size_t)(wave*2 + ee) * N + col0 + prow) * KE + kcl * 8;

    // B frag-read lane constant: stored chunk for global chunk q=quad of row n:
    // c = quad ^ ((n>>1)&3); (n>>1)&3 == (ln>>1)&3 (16-aligned tiles)
    const int csel = quad ^ ((ln >> 1) & 3);

    f32x4 acc[2][4] = {};

    for (int k0 = 0; k0 < KE; k0 += 32) {
        __syncthreads();   // protect LDS from previous iteration's readers

        // B tiles: 8 experts x 128 x 32 f16 via 16 glds/thread (async)
        #pragma unroll
        for (int ee = 0; ee < 2; ++ee) {
            const int e = wave * 2 + ee;
            #pragma unroll
            for (int j = 0; j < 8; ++j) {
                glds16(wb[ee] + k0 + (size_t)j * 16 * KE,
                       &b_sh[(e * 128 + j * 16) * 32]);
            }
        }

        // A tile 64x32 (unscaled) through VGPRs
        f16x8 av;
        if (SRC == 0) {
            int k = k0 + ac * 8;   // 800 % 8 == 0: chunk is pure-x or pure-z
            const float* s = (k < XDIM)
                ? x + (size_t)(row0 + ar) * XDIM + k
                : z + (size_t)(row0 + ar) * ZDIM + (k - XDIM);
            float4 v0 = *(const float4*)s;
            float4 v1 = *(const float4*)(s + 4);
            av = (f16x8){ (f16)v0.x,(f16)v0.y,(f16)v0.z,(f16)v0.w,
                          (f16)v1.x,(f16)v1.y,(f16)v1.z,(f16)v1.w };
        } else {
            av = *(const f16x8*)(A + (size_t)(row0 + ar) * ldA + k0 + ac * 8);
        }
        *(f16x8*)&a_sh[ar][ac * 8] = av;

        __syncthreads();   // waits vmcnt(0): glds data + ds_write visible

        f16x8 af0 = *(const f16x8*)&a_sh[wy*32 +      ln][quad * 8];
        f16x8 af1 = *(const f16x8*)&a_sh[wy*32 + 16 + ln][quad * 8];

        #pragma unroll
        for (int e = 0; e < NEXP; ++e) {
            f16x8 bf[4];
            #pragma unroll
            for (int ni = 0; ni < 4; ++ni) {
                int n = wx*64 + ni*16 + ln;
                bf[ni] = *(const f16x8*)&b_sh[e*4096 + n*32 + csel*8];
            }
            f16x8 a0 = vscale(af0, bcf[0][e]);
            f16x8 a1 = vscale(af1, bcf[1][e]);
            #pragma unroll
            for (int ni = 0; ni < 4; ++ni) {
                acc[0][ni] = __builtin_amdgcn_mfma_f32_16x16x32_f16(
                    a0, bf[ni], acc[0][ni], 0, 0, 0);
                acc[1][ni] = __builtin_amdgcn_mfma_f32_16x16x32_f16(
                    a1, bf[ni], acc[1][ni], 0, 0, 0);
            }
        }
    }

    // epilogue: + sum_e bc*bias, activation, store
    #pragma unroll
    for (int mi = 0; mi < 2; ++mi)
        #pragma unroll
        for (int r = 0; r < 4; ++r) {
            int rl = wy*32 + mi*16 + quad*4 + r;
            size_t grow = (size_t)(row0 + rl) * ldOut;
            #pragma unroll
            for (int ni = 0; ni < 4; ++ni) {
                int cl = wx*64 + ni*16 + ln;
                float v = acc[mi][ni][r];
                #pragma unroll
                for (int e2 = 0; e2 < NEXP; ++e2)
                    v += bc_sh[rl][e2] * bias_sh[e2][cl];
                if (ACT) v = elu_act(v);
                out[grow + col0 + cl] = (OT)v;
            }
        }
}

// ===========================================================================
extern "C" void kernel_launch(void* const* d_in, const int* in_sizes, int n_in,
                              void* d_out, int out_size, void* d_ws, size_t ws_size,
                              hipStream_t stream)
{
    const float* x   = (const float*)d_in[0];
    const float* z   = (const float*)d_in[1];
    const float* Wg1 = (const float*)d_in[2];
    const float* bg1 = (const float*)d_in[3];
    const float* Wg2 = (const float*)d_in[4];
    const float* bg2 = (const float*)d_in[5];
    const float* Wg3 = (const float*)d_in[6];
    const float* bg3 = (const float*)d_in[7];
    const float* W0  = (const float*)d_in[8];
    const float* b0  = (const float*)d_in[9];
    const float* W1  = (const float*)d_in[10];
    const float* b1  = (const float*)d_in[11];
    const float* W2  = (const float*)d_in[12];
    const float* b2  = (const float*)d_in[13];
    const float* W3  = (const float*)d_in[14];
    const float* b3  = (const float*)d_in[15];
    float* out = (float*)d_out;

    // workspace (~40 MB): wbuf f16 [8*1024*1088], hz_a/hz_b f16 [4096][1088],
    // g1/g2 f32 [4096][128], bc f32 [4096][8]
    char* ws = (char*)d_ws;
    f16*   wbuf = (f16*)ws;                 ws += (size_t)NEXP * HDIM * (HDIM + ZDIM) * 2;
    f16*   hz_a = (f16*)ws;                 ws += (size_t)BDIM * (HDIM + ZDIM) * 2;
    f16*   hz_b = (f16*)ws;                 ws += (size_t)BDIM * (HDIM + ZDIM) * 2;
    float* g1   = (float*)ws;               ws += (size_t)BDIM * GH * 4;
    float* g2   = (float*)ws;               ws += (size_t)BDIM * GH * 4;
    float* bcw  = (float*)ws;

    dim3 blk(256);

    // z-columns of hz buffers
    fill_z<<<dim3(BDIM * ZDIM / 4 / 256), blk, 0, stream>>>(z, hz_a, hz_b);

    // gating MLP (fp32)
    gemm_cat<1><<<dim3(BDIM/BMg, GH/BNg), blk, 0, stream>>>(x, XDIM, z, ZDIM, Wg1, bg1, g1, GH);
    gemm_cat<1><<<dim3(BDIM/BMg, GH/BNg), blk, 0, stream>>>(g1, GH, nullptr, 0, Wg2, bg2, g2, GH);
    gating3_softmax<<<dim3(BDIM/32), blk, 0, stream>>>(g2, Wg3, bg3, bcw);

    // blended expert layers: convert weights to f16, then big-K MFMA GEMM
    w_to_f16<<<dim3(NEXP*HDIM*(XDIM+ZDIM)/8/256), blk, 0, stream>>>(W0, wbuf);
    blended_big<XDIM+ZDIM, HDIM, 1, 0, f16><<<dim3(64 * 8), blk, 0, stream>>>(
        nullptr, 0, x, z, wbuf, b0, bcw, hz_a, HDIM + ZDIM);

    w_to_f16<<<dim3(NEXP*HDIM*(HDIM+ZDIM)/8/256), blk, 0, stream>>>(W1, wbuf);
    blended_big<HDIM+ZDIM, HDIM, 1, 1, f16><<<dim3(64 * 8), blk, 0, stream>>>(
        hz_a, HDIM + ZDIM, nullptr, nullptr, wbuf, b1, bcw, hz_b, HDIM + ZDIM);

    w_to_f16<<<dim3(NEXP*HDIM*(HDIM+ZDIM)/8/256), blk, 0, stream>>>(W2, wbuf);
    blended_big<HDIM+ZDIM, HDIM, 1, 1, f16><<<dim3(64 * 8), blk, 0, stream>>>(
        hz_b, HDIM + ZDIM, nullptr, nullptr, wbuf, b2, bcw, hz_a, HDIM + ZDIM);

    w_to_f16<<<dim3(NEXP*ODIM*HDIM/8/256), blk, 0, stream>>>(W3, wbuf);
    blended_big<HDIM, ODIM, 0, 1, float><<<dim3(64 * 6), blk, 0, stream>>>(
        hz_a, HDIM + ZDIM, nullptr, nullptr, wbuf, b3, bcw, out, ODIM);
}